// Round 3
// baseline (102.813 us; speedup 1.0000x reference)
//
#include <hip/hip_runtime.h>
#include <stdint.h>
#include <limits.h>

// Problem constants (B, C, H, W fixed by the reference)
#define Bn      16
#define Nn      5242880            // 80*256*256 elements per batch
#define KK      100                // TOPK
#define BPB     128                // blocks per batch for the streaming pass
#define CHUNK   (Nn / BPB)         // 40960 elements per block
#define SLOT    24                 // per-block candidate capacity (mean ~1.3 @ T0=4.0)
#define SORTCAP 2048               // guard-path sort capacity
#define RANKCAP 256                // fast-path rank-selection capacity (mean ~166)
#define NBINS   4096               // fallback radix bins
#define T0      4.0f               // fast-path threshold (top-100 cutoff ~4.11 for N(0,1))
#define FTH     256                // block size

typedef float f4v __attribute__((ext_vector_type(4)));

#define ST_AGENT(p, v) __hip_atomic_store((p), (v), __ATOMIC_RELAXED, __HIP_MEMORY_SCOPE_AGENT)
#define LD_AGENT(p)    __hip_atomic_load((p), __ATOMIC_RELAXED, __HIP_MEMORY_SCOPE_AGENT)

__device__ __forceinline__ unsigned fkey(unsigned u) {
    // monotone float->uint transform: larger float => larger key
    return (u & 0x80000000u) ? ~u : (u | 0x80000000u);
}

// ---------- emit one detection at a given rank ----------
__device__ __forceinline__ void emit_one(int b, int rank, float val, int idx,
                                         const float* __restrict__ wh,
                                         const float* __restrict__ reg,
                                         float* __restrict__ out) {
    float* out_cls = out;                 // [16][100]
    float* out_scr = out + Bn * KK;       // [16][100]
    float* out_res = out + 2 * Bn * KK;   // [16][100][4]
    out_cls[b * KK + rank] = (float)idx * (1.0f / 65536.0f);  // exact pow2 division
    out_scr[b * KK + rank] = val;
    const int s  = idx & 65535;
    const float tys = (float)s * (1.0f / 256.0f);             // topk_indices / W (exact)
    const float txs = (float)(s & 255);                       // topk_indices % W
    // reg/wh layout [B,2,H,W]: channel-c at (b, s) = ptr[(b*2+c)*65536 + s]
    const float xo = reg[(size_t)(b * 2 + 0) * 65536 + s];
    const float yo = reg[(size_t)(b * 2 + 1) * 65536 + s];
    const float ww = wh [(size_t)(b * 2 + 0) * 65536 + s];
    const float hh = wh [(size_t)(b * 2 + 1) * 65536 + s];
    const float cx = txs + xo;
    const float cy = tys + yo;
    const float hw  = ww * 0.5f;
    const float hh2 = hh * 0.5f;
    float* r = out_res + (size_t)(b * KK + rank) * 4;
    r[0] = (cx - hw)  * 4.0f;
    r[1] = (cy - hh2) * 4.0f;
    r[2] = (cx + hw)  * 4.0f;
    r[3] = (cy + hh2) * 4.0f;
}

// ---------- fused: stream-collect + last-block-per-batch finalize ------------
// Cross-block visibility WITHOUT any fence/wbl2/inv:
//   writers:  sc1 agent-scope stores (write-through to IF coherence point)
//   ordering: __syncthreads() drains every wave's vmcnt(0); t0 then stores
//             bcnt (sc1), waits its own vmcnt(0), and takes a relaxed
//             agent-scope ticket. Same-address RMW chain => message passing.
//   reader:   agent-scope loads (sc0+sc1) bypass possibly-stale L0/L2.
// LDS ~17.2 KiB (hist UNION {sv,si}) -> 8 blocks/CU retained.
__global__ __launch_bounds__(FTH, 8) void k_fused(const float* __restrict__ x,
                                                  const float* __restrict__ wh,
                                                  const float* __restrict__ reg,
                                                  int* __restrict__ done,
                                                  int* __restrict__ bcnt,
                                                  float* __restrict__ cval,
                                                  int* __restrict__ cidx,
                                                  float* __restrict__ out) {
    const int b = blockIdx.y, blk = blockIdx.x;
    const int t = threadIdx.x;

    __shared__ int lcnt;
    __shared__ int amlast;
    __shared__ __align__(16) int uw[2 * SORTCAP];   // 16 KiB: hist[4096] OR {sv,si}
    __shared__ int pscan[BPB];
    __shared__ int cnt_s[BPB];
    __shared__ int wtot2[2];
    __shared__ int sflags;
    __shared__ int scnt;
    __shared__ unsigned stk;

    // ================= collect phase (every block) =================
    if (t == 0) lcnt = 0;
    __syncthreads();
    {
        const f4v* xv = reinterpret_cast<const f4v*>(
            x + (size_t)b * Nn + (size_t)blk * CHUNK);
        const int base = blk * CHUNK;
        float* v  = cval + ((size_t)b * BPB + blk) * SLOT;
        int*   ix = cidx + ((size_t)b * BPB + blk) * SLOT;
#pragma unroll 4
        for (int j = t; j < CHUNK / 4; j += FTH) {
            f4v f = __builtin_nontemporal_load(&xv[j]);   // streaming read, no reuse
            const float m = fmaxf(fmaxf(f.x, f.y), fmaxf(f.z, f.w));
            if (m >= T0) {                                 // ~1.3e-4 per-lane: rare
                const int i0 = base + 4 * j;
                if (f.x >= T0) { int p = atomicAdd(&lcnt, 1); if (p < SLOT) { ST_AGENT(&v[p], f.x); ST_AGENT(&ix[p], i0);     } }
                if (f.y >= T0) { int p = atomicAdd(&lcnt, 1); if (p < SLOT) { ST_AGENT(&v[p], f.y); ST_AGENT(&ix[p], i0 + 1); } }
                if (f.z >= T0) { int p = atomicAdd(&lcnt, 1); if (p < SLOT) { ST_AGENT(&v[p], f.z); ST_AGENT(&ix[p], i0 + 2); } }
                if (f.w >= T0) { int p = atomicAdd(&lcnt, 1); if (p < SLOT) { ST_AGENT(&v[p], f.w); ST_AGENT(&ix[p], i0 + 3); } }
            }
        }
    }
    __syncthreads();   // every wave: s_waitcnt vmcnt(0) -> all sc1 stores at IF
    if (t == 0) {
        ST_AGENT(&bcnt[b * BPB + blk], lcnt);
        asm volatile("s_waitcnt vmcnt(0)" ::: "memory");   // own bcnt store retired
        const int old = __hip_atomic_fetch_add(&done[b], 1, __ATOMIC_RELAXED,
                                               __HIP_MEMORY_SCOPE_AGENT);
        amlast = (old == BPB - 1) ? 1 : 0;
        sflags = 0; scnt = 0;        // init finalize scalars under the barrier
    }
    __syncthreads();
    if (!amlast) return;

    // ================= finalize phase (1 block per batch) =================
    float* sv   = (float*)uw;          // uw[0..2047]
    int*   si   = uw + SORTCAP;        // uw[2048..4095]
    int*   hist = uw;                  // fallback phase 1 only (before sv/si init)

    // ---- 2-wave shuffle scan over BPB=128 counts (coherent bcnt loads) ----
    int myscan = 0, myc = 0;
    if (t < BPB) {
        myc = LD_AGENT(&bcnt[b * BPB + t]);
        if (myc > SLOT) atomicOr(&sflags, 1);
        cnt_s[t] = myc;
        int v2 = myc;
#pragma unroll
        for (int d = 1; d < 64; d <<= 1) {
            int u = __shfl_up(v2, d);
            if ((t & 63) >= d) v2 += u;
        }
        if ((t & 63) == 63) wtot2[t >> 6] = v2;
        myscan = v2;
    }
    __syncthreads();
    if (t < BPB) pscan[t] = myscan + ((t >= 64) ? wtot2[0] : 0);
    __syncthreads();

    const int total_all = pscan[BPB - 1];
    const bool bad = (sflags != 0) || (total_all < KK) || (total_all > SORTCAP);

    const float NEG_INF = __int_as_float(0xFF800000);
    int n;
    if (!bad) {
        n = total_all;
        for (int i = t; i < SORTCAP; i += FTH) { sv[i] = NEG_INF; si[i] = INT_MAX; }
        __syncthreads();
        if (t < BPB) {
            const int off = pscan[t] - myc;   // exclusive prefix
            const float* vp = cval + ((size_t)b * BPB + t) * SLOT;
            const int*   ip = cidx + ((size_t)b * BPB + t) * SLOT;
            for (int i = 0; i < myc; ++i) {
                sv[off + i] = LD_AGENT(&vp[i]);
                si[off + i] = LD_AGENT(&ip[i]);
            }
        }
        __syncthreads();
    } else {
        // ---- robust fallback: LDS-histogram top-k over full batch (never-path)
        // Phase 1: histogram owns the whole union buffer; sv/si init AFTER.
        for (int i = t; i < NBINS; i += FTH) hist[i] = 0;
        __syncthreads();
        const float4* xv4 = reinterpret_cast<const float4*>(x + (size_t)b * Nn);
        for (int j = t; j < Nn / 4; j += FTH) {
            float4 f = xv4[j];
            atomicAdd(&hist[fkey(__float_as_uint(f.x)) >> 20], 1);
            atomicAdd(&hist[fkey(__float_as_uint(f.y)) >> 20], 1);
            atomicAdd(&hist[fkey(__float_as_uint(f.z)) >> 20], 1);
            atomicAdd(&hist[fkey(__float_as_uint(f.w)) >> 20], 1);
        }
        __syncthreads();
        if (t == 0) {
            int cum = 0; unsigned k2 = 0;
            for (int bin = NBINS - 1; bin >= 0; --bin) {
                cum += hist[bin];
                if (cum >= KK) { k2 = (unsigned)bin << 20; break; }
            }
            stk = k2;
        }
        __syncthreads();
        const unsigned tk = stk;
        // Phase 2: overwrite union buffer with sv/si and re-collect above threshold
        for (int i = t; i < SORTCAP; i += FTH) { sv[i] = NEG_INF; si[i] = INT_MAX; }
        __syncthreads();
        for (int j = t; j < Nn / 4; j += FTH) {
            float4 f = xv4[j];
            const int i0 = 4 * j;
            float a[4] = {f.x, f.y, f.z, f.w};
#pragma unroll
            for (int cc = 0; cc < 4; ++cc) {
                if (fkey(__float_as_uint(a[cc])) >= tk) {
                    int p = atomicAdd(&scnt, 1);
                    if (p < SORTCAP) { sv[p] = a[cc]; si[p] = i0 + cc; }
                }
            }
        }
        __syncthreads();
        n = scnt; if (n > SORTCAP) n = SORTCAP;
    }

    if (!bad && n <= RANKCAP) {
        // ---- fast path: exact rank via O(n^2) broadcast compares, 1 barrier --
        const float myv = sv[t];          // t in [0,256): own candidate (or pad)
        const int   myi = si[t];
        int rank = 0;
#pragma unroll 8
        for (int j = 0; j < RANKCAP; ++j) {
            const float vj = sv[j];       // LDS broadcast: all lanes same addr
            const int   ij = si[j];
            rank += ((vj > myv) || (vj == myv && ij < myi)) ? 1 : 0;
        }
        if (rank < KK) emit_one(b, rank, myv, myi, wh, reg, out);
        return;
    }

    // ---- guard path: bitonic sort (value desc, tie -> index asc) ------------
    int pad = FTH;
    while (pad < n) pad <<= 1;     // <= SORTCAP
    for (int k = 2; k <= pad; k <<= 1) {
        for (int j = k >> 1; j > 0; j >>= 1) {
            for (int i = t; i < pad; i += FTH) {
                const int ixj = i ^ j;
                if (ixj > i) {
                    float va = sv[i], vb = sv[ixj];
                    int   ia = si[i], ib = si[ixj];
                    const bool a_before_b = (va > vb) || (va == vb && ia < ib);
                    const bool dir = ((i & k) == 0);
                    if (dir ? !a_before_b : a_before_b) {
                        sv[i] = vb; sv[ixj] = va; si[i] = ib; si[ixj] = ia;
                    }
                }
            }
            __syncthreads();
        }
    }
    for (int j = t; j < KK; j += FTH) emit_one(b, j, sv[j], si[j], wh, reg, out);
}

extern "C" void kernel_launch(void* const* d_in, const int* in_sizes, int n_in,
                              void* d_out, int out_size, void* d_ws, size_t ws_size,
                              hipStream_t stream) {
    const float* x   = (const float*)d_in[0];
    const float* wh  = (const float*)d_in[1];
    const float* reg = (const float*)d_in[2];
    float* out = (float*)d_out;

    // workspace layout: bcnt [16][128] at 0, done [16] at +8 KiB,
    // candidate arrays at +16 KiB.
    char* ws = (char*)d_ws;
    int*   bcnt = (int*)(ws);                                        // [16][128]
    int*   done = (int*)(ws + 8 * 1024);                             // [16]
    float* cval = (float*)(ws + 16 * 1024);                          // [16][128][24]
    int*   cidx = (int*)(ws + 16 * 1024 + (size_t)Bn * BPB * SLOT * 4);

    // per-launch ticket reset (64 B; graph-capturable stream op)
    hipMemsetAsync(done, 0, Bn * sizeof(int), stream);

    dim3 grid(BPB, Bn);
    k_fused<<<grid, FTH, 0, stream>>>(x, wh, reg, done, bcnt, cval, cidx, out);
}

// Round 4
// 102.223 us; speedup vs baseline: 1.0058x; 1.0058x over previous
//
#include <hip/hip_runtime.h>
#include <stdint.h>
#include <limits.h>

// Problem constants (B, C, H, W fixed by the reference)
#define Bn      16
#define Nn      5242880            // 80*256*256 elements per batch
#define KK      100                // TOPK
#define BPB     128                // blocks per batch for the streaming pass
#define CHUNK   (Nn / BPB)         // 40960 elements per block
#define SLOT    24                 // per-block candidate capacity (mean ~1.3 @ T0=4.0)
#define SORTCAP 2048               // guard-path sort capacity
#define RANKCAP 256                // fast-path rank-selection capacity (mean ~166)
#define NBINS   4096               // fallback radix bins
#define T0      4.0f               // fast-path threshold (top-100 cutoff ~4.11 for N(0,1))
#define FTH     256                // block size

typedef float f4v __attribute__((ext_vector_type(4)));

#define ST_AGENT(p, v) __hip_atomic_store((p), (v), __ATOMIC_RELAXED, __HIP_MEMORY_SCOPE_AGENT)
#define LD_AGENT(p)    __hip_atomic_load((p), __ATOMIC_RELAXED, __HIP_MEMORY_SCOPE_AGENT)

__device__ __forceinline__ unsigned fkey(unsigned u) {
    // monotone float->uint transform: larger float => larger key
    return (u & 0x80000000u) ? ~u : (u | 0x80000000u);
}

// ---------- tiny ticket-reset kernel (replaces hipMemsetAsync: the memset
// node was costing ~40 us of cross-engine/cache-maintenance overhead) -------
__global__ __launch_bounds__(64) void k_reset(int* __restrict__ done) {
    if (threadIdx.x < Bn) done[threadIdx.x] = 0;
}

// ---------- emit one detection at a given rank ----------
__device__ __forceinline__ void emit_one(int b, int rank, float val, int idx,
                                         const float* __restrict__ wh,
                                         const float* __restrict__ reg,
                                         float* __restrict__ out) {
    float* out_cls = out;                 // [16][100]
    float* out_scr = out + Bn * KK;       // [16][100]
    float* out_res = out + 2 * Bn * KK;   // [16][100][4]
    out_cls[b * KK + rank] = (float)idx * (1.0f / 65536.0f);  // exact pow2 division
    out_scr[b * KK + rank] = val;
    const int s  = idx & 65535;
    const float tys = (float)s * (1.0f / 256.0f);             // topk_indices / W (exact)
    const float txs = (float)(s & 255);                       // topk_indices % W
    // reg/wh layout [B,2,H,W]: channel-c at (b, s) = ptr[(b*2+c)*65536 + s]
    const float xo = reg[(size_t)(b * 2 + 0) * 65536 + s];
    const float yo = reg[(size_t)(b * 2 + 1) * 65536 + s];
    const float ww = wh [(size_t)(b * 2 + 0) * 65536 + s];
    const float hh = wh [(size_t)(b * 2 + 1) * 65536 + s];
    const float cx = txs + xo;
    const float cy = tys + yo;
    const float hw  = ww * 0.5f;
    const float hh2 = hh * 0.5f;
    float* r = out_res + (size_t)(b * KK + rank) * 4;
    r[0] = (cx - hw)  * 4.0f;
    r[1] = (cy - hh2) * 4.0f;
    r[2] = (cx + hw)  * 4.0f;
    r[3] = (cy + hh2) * 4.0f;
}

// ---------- fused: stream-collect + last-block-per-batch finalize ------------
// Cross-block visibility WITHOUT any fence/wbl2/inv:
//   writers:  sc1 agent-scope stores (write-through to IF coherence point)
//   ordering: __syncthreads() drains every wave's vmcnt(0); t0 then stores
//             bcnt (sc1), waits its own vmcnt(0), and takes a relaxed
//             agent-scope ticket. Same-address RMW chain => message passing.
//   reader:   agent-scope loads (sc0+sc1) bypass possibly-stale L0/L2.
// LDS ~17.2 KiB (hist UNION {sv,si}) -> 8 blocks/CU retained.
__global__ __launch_bounds__(FTH, 8) void k_fused(const float* __restrict__ x,
                                                  const float* __restrict__ wh,
                                                  const float* __restrict__ reg,
                                                  int* __restrict__ done,
                                                  int* __restrict__ bcnt,
                                                  float* __restrict__ cval,
                                                  int* __restrict__ cidx,
                                                  float* __restrict__ out) {
    const int b = blockIdx.y, blk = blockIdx.x;
    const int t = threadIdx.x;

    __shared__ int lcnt;
    __shared__ int amlast;
    __shared__ __align__(16) int uw[2 * SORTCAP];   // 16 KiB: hist[4096] OR {sv,si}
    __shared__ int pscan[BPB];
    __shared__ int cnt_s[BPB];
    __shared__ int wtot2[2];
    __shared__ int sflags;
    __shared__ int scnt;
    __shared__ unsigned stk;

    // ================= collect phase (every block) =================
    if (t == 0) lcnt = 0;
    __syncthreads();
    {
        const f4v* xv = reinterpret_cast<const f4v*>(
            x + (size_t)b * Nn + (size_t)blk * CHUNK);
        const int base = blk * CHUNK;
        float* v  = cval + ((size_t)b * BPB + blk) * SLOT;
        int*   ix = cidx + ((size_t)b * BPB + blk) * SLOT;
#pragma unroll 4
        for (int j = t; j < CHUNK / 4; j += FTH) {
            f4v f = __builtin_nontemporal_load(&xv[j]);   // streaming read, no reuse
            const float m = fmaxf(fmaxf(f.x, f.y), fmaxf(f.z, f.w));
            if (m >= T0) {                                 // ~1.3e-4 per-lane: rare
                const int i0 = base + 4 * j;
                if (f.x >= T0) { int p = atomicAdd(&lcnt, 1); if (p < SLOT) { ST_AGENT(&v[p], f.x); ST_AGENT(&ix[p], i0);     } }
                if (f.y >= T0) { int p = atomicAdd(&lcnt, 1); if (p < SLOT) { ST_AGENT(&v[p], f.y); ST_AGENT(&ix[p], i0 + 1); } }
                if (f.z >= T0) { int p = atomicAdd(&lcnt, 1); if (p < SLOT) { ST_AGENT(&v[p], f.z); ST_AGENT(&ix[p], i0 + 2); } }
                if (f.w >= T0) { int p = atomicAdd(&lcnt, 1); if (p < SLOT) { ST_AGENT(&v[p], f.w); ST_AGENT(&ix[p], i0 + 3); } }
            }
        }
    }
    __syncthreads();   // every wave: s_waitcnt vmcnt(0) -> all sc1 stores at IF
    if (t == 0) {
        ST_AGENT(&bcnt[b * BPB + blk], lcnt);
        asm volatile("s_waitcnt vmcnt(0)" ::: "memory");   // own bcnt store retired
        const int old = __hip_atomic_fetch_add(&done[b], 1, __ATOMIC_RELAXED,
                                               __HIP_MEMORY_SCOPE_AGENT);
        amlast = (old == BPB - 1) ? 1 : 0;
        sflags = 0; scnt = 0;        // init finalize scalars under the barrier
    }
    __syncthreads();
    if (!amlast) return;

    // ================= finalize phase (1 block per batch) =================
    float* sv   = (float*)uw;          // uw[0..2047]
    int*   si   = uw + SORTCAP;        // uw[2048..4095]
    int*   hist = uw;                  // fallback phase 1 only (before sv/si init)

    // ---- 2-wave shuffle scan over BPB=128 counts (coherent bcnt loads) ----
    int myscan = 0, myc = 0;
    if (t < BPB) {
        myc = LD_AGENT(&bcnt[b * BPB + t]);
        if (myc > SLOT) atomicOr(&sflags, 1);
        cnt_s[t] = myc;
        int v2 = myc;
#pragma unroll
        for (int d = 1; d < 64; d <<= 1) {
            int u = __shfl_up(v2, d);
            if ((t & 63) >= d) v2 += u;
        }
        if ((t & 63) == 63) wtot2[t >> 6] = v2;
        myscan = v2;
    }
    __syncthreads();
    if (t < BPB) pscan[t] = myscan + ((t >= 64) ? wtot2[0] : 0);
    __syncthreads();

    const int total_all = pscan[BPB - 1];
    const bool bad = (sflags != 0) || (total_all < KK) || (total_all > SORTCAP);

    const float NEG_INF = __int_as_float(0xFF800000);
    int n;
    if (!bad) {
        n = total_all;
        for (int i = t; i < SORTCAP; i += FTH) { sv[i] = NEG_INF; si[i] = INT_MAX; }
        __syncthreads();
        if (t < BPB) {
            const int off = pscan[t] - myc;   // exclusive prefix
            const float* vp = cval + ((size_t)b * BPB + t) * SLOT;
            const int*   ip = cidx + ((size_t)b * BPB + t) * SLOT;
            for (int i = 0; i < myc; ++i) {
                sv[off + i] = LD_AGENT(&vp[i]);
                si[off + i] = LD_AGENT(&ip[i]);
            }
        }
        __syncthreads();
    } else {
        // ---- robust fallback: LDS-histogram top-k over full batch (never-path)
        // Phase 1: histogram owns the whole union buffer; sv/si init AFTER.
        for (int i = t; i < NBINS; i += FTH) hist[i] = 0;
        __syncthreads();
        const float4* xv4 = reinterpret_cast<const float4*>(x + (size_t)b * Nn);
        for (int j = t; j < Nn / 4; j += FTH) {
            float4 f = xv4[j];
            atomicAdd(&hist[fkey(__float_as_uint(f.x)) >> 20], 1);
            atomicAdd(&hist[fkey(__float_as_uint(f.y)) >> 20], 1);
            atomicAdd(&hist[fkey(__float_as_uint(f.z)) >> 20], 1);
            atomicAdd(&hist[fkey(__float_as_uint(f.w)) >> 20], 1);
        }
        __syncthreads();
        if (t == 0) {
            int cum = 0; unsigned k2 = 0;
            for (int bin = NBINS - 1; bin >= 0; --bin) {
                cum += hist[bin];
                if (cum >= KK) { k2 = (unsigned)bin << 20; break; }
            }
            stk = k2;
        }
        __syncthreads();
        const unsigned tk = stk;
        // Phase 2: overwrite union buffer with sv/si and re-collect above threshold
        for (int i = t; i < SORTCAP; i += FTH) { sv[i] = NEG_INF; si[i] = INT_MAX; }
        __syncthreads();
        for (int j = t; j < Nn / 4; j += FTH) {
            float4 f = xv4[j];
            const int i0 = 4 * j;
            float a[4] = {f.x, f.y, f.z, f.w};
#pragma unroll
            for (int cc = 0; cc < 4; ++cc) {
                if (fkey(__float_as_uint(a[cc])) >= tk) {
                    int p = atomicAdd(&scnt, 1);
                    if (p < SORTCAP) { sv[p] = a[cc]; si[p] = i0 + cc; }
                }
            }
        }
        __syncthreads();
        n = scnt; if (n > SORTCAP) n = SORTCAP;
    }

    if (!bad && n <= RANKCAP) {
        // ---- fast path: exact rank via O(n^2) broadcast compares, 1 barrier --
        const float myv = sv[t];          // t in [0,256): own candidate (or pad)
        const int   myi = si[t];
        int rank = 0;
#pragma unroll 8
        for (int j = 0; j < RANKCAP; ++j) {
            const float vj = sv[j];       // LDS broadcast: all lanes same addr
            const int   ij = si[j];
            rank += ((vj > myv) || (vj == myv && ij < myi)) ? 1 : 0;
        }
        if (rank < KK) emit_one(b, rank, myv, myi, wh, reg, out);
        return;
    }

    // ---- guard path: bitonic sort (value desc, tie -> index asc) ------------
    int pad = FTH;
    while (pad < n) pad <<= 1;     // <= SORTCAP
    for (int k = 2; k <= pad; k <<= 1) {
        for (int j = k >> 1; j > 0; j >>= 1) {
            for (int i = t; i < pad; i += FTH) {
                const int ixj = i ^ j;
                if (ixj > i) {
                    float va = sv[i], vb = sv[ixj];
                    int   ia = si[i], ib = si[ixj];
                    const bool a_before_b = (va > vb) || (va == vb && ia < ib);
                    const bool dir = ((i & k) == 0);
                    if (dir ? !a_before_b : a_before_b) {
                        sv[i] = vb; sv[ixj] = va; si[i] = ib; si[ixj] = ia;
                    }
                }
            }
            __syncthreads();
        }
    }
    for (int j = t; j < KK; j += FTH) emit_one(b, j, sv[j], si[j], wh, reg, out);
}

extern "C" void kernel_launch(void* const* d_in, const int* in_sizes, int n_in,
                              void* d_out, int out_size, void* d_ws, size_t ws_size,
                              hipStream_t stream) {
    const float* x   = (const float*)d_in[0];
    const float* wh  = (const float*)d_in[1];
    const float* reg = (const float*)d_in[2];
    float* out = (float*)d_out;

    // workspace layout: bcnt [16][128] at 0, done [16] at +8 KiB,
    // candidate arrays at +16 KiB.
    char* ws = (char*)d_ws;
    int*   bcnt = (int*)(ws);                                        // [16][128]
    int*   done = (int*)(ws + 8 * 1024);                             // [16]
    float* cval = (float*)(ws + 16 * 1024);                          // [16][128][24]
    int*   cidx = (int*)(ws + 16 * 1024 + (size_t)Bn * BPB * SLOT * 4);

    // per-launch ticket reset via a COMPUTE kernel (memset node was ~40 us)
    k_reset<<<1, 64, 0, stream>>>(done);

    dim3 grid(BPB, Bn);
    k_fused<<<grid, FTH, 0, stream>>>(x, wh, reg, done, bcnt, cval, cidx, out);
}

// Round 5
// 69.868 us; speedup vs baseline: 1.4715x; 1.4631x over previous
//
#include <hip/hip_runtime.h>
#include <stdint.h>
#include <limits.h>

// Problem constants (B, C, H, W fixed by the reference)
#define Bn      16
#define Nn      5242880            // 80*256*256 elements per batch
#define KK      100                // TOPK
#define BPB     128                // blocks per batch for the streaming pass
#define CHUNK   (Nn / BPB)         // 40960 elements per block
#define SLOT    24                 // per-block candidate capacity (mean ~1.3 @ T0=4.0)
#define NSLOTS  (BPB * SLOT)       // 3072 slots per batch
#define SPT     (NSLOTS / 256)     // 12 speculative slots per thread
#define SORTCAP 2048               // guard-path sort capacity
#define RANKCAP 256                // fast-path rank-selection capacity (mean ~166)
#define NBINS   4096               // fallback radix bins
#define T0      4.0f               // fast-path threshold (top-100 cutoff ~4.11 for N(0,1))
#define FTH     256                // k_final block size

typedef float f8v __attribute__((ext_vector_type(8)));

__device__ __forceinline__ unsigned fkey(unsigned u) {
    // monotone float->uint transform: larger float => larger key
    return (u & 0x80000000u) ? ~u : (u | 0x80000000u);
}

// ---------- pass 1: stream x once, per-block private candidate slots ---------
// R5 change vs the 62.35us R2 version: plain (cacheable) loads instead of
// nontemporal, 32 B/lane/iter (2x dwordx4) instead of 16 B. k_final untouched.
__global__ __launch_bounds__(256) void k_collect(const float* __restrict__ x,
                                                 int* __restrict__ bcnt,
                                                 float* __restrict__ cval,
                                                 int* __restrict__ cidx) {
    const int b = blockIdx.y, blk = blockIdx.x;
    __shared__ int lcnt;
    if (threadIdx.x == 0) lcnt = 0;
    __syncthreads();
    const f8v* xv = reinterpret_cast<const f8v*>(
        x + (size_t)b * Nn + (size_t)blk * CHUNK);
    const int base = blk * CHUNK;
    float* v  = cval + ((size_t)b * BPB + blk) * SLOT;
    int*   ix = cidx + ((size_t)b * BPB + blk) * SLOT;
#pragma unroll 4
    for (int j = threadIdx.x; j < CHUNK / 8; j += 256) {
        f8v f = xv[j];                                // 32 B: 2x global_load_dwordx4
        const float m0 = fmaxf(fmaxf(f[0], f[1]), fmaxf(f[2], f[3]));
        const float m1 = fmaxf(fmaxf(f[4], f[5]), fmaxf(f[6], f[7]));
        if (fmaxf(m0, m1) >= T0) {                    // ~2.5e-4 per-lane: rare
            const int i0 = base + 8 * j;
#pragma unroll
            for (int c = 0; c < 8; ++c) {
                if (f[c] >= T0) {
                    int p = atomicAdd(&lcnt, 1);
                    if (p < SLOT) { v[p] = f[c]; ix[p] = i0 + c; }
                }
            }
        }
    }
    __syncthreads();
    if (threadIdx.x == 0) bcnt[b * BPB + blk] = lcnt;   // unconditional: no zeroing needed
}

// ---------- emit one detection at a given rank ----------
__device__ __forceinline__ void emit_one(int b, int rank, float val, int idx,
                                         const float* __restrict__ wh,
                                         const float* __restrict__ reg,
                                         float* __restrict__ out) {
    float* out_cls = out;                 // [16][100]
    float* out_scr = out + Bn * KK;       // [16][100]
    float* out_res = out + 2 * Bn * KK;   // [16][100][4]
    out_cls[b * KK + rank] = (float)idx * (1.0f / 65536.0f);  // exact pow2 division
    out_scr[b * KK + rank] = val;
    const int s  = idx & 65535;
    const float tys = (float)s * (1.0f / 256.0f);             // topk_indices / W (exact)
    const float txs = (float)(s & 255);                       // topk_indices % W
    // reg/wh layout [B,2,H,W]: channel-c at (b, s) = ptr[(b*2+c)*65536 + s]
    const float xo = reg[(size_t)(b * 2 + 0) * 65536 + s];
    const float yo = reg[(size_t)(b * 2 + 1) * 65536 + s];
    const float ww = wh [(size_t)(b * 2 + 0) * 65536 + s];
    const float hh = wh [(size_t)(b * 2 + 1) * 65536 + s];
    const float cx = txs + xo;
    const float cy = tys + yo;
    const float hw  = ww * 0.5f;
    const float hh2 = hh * 0.5f;
    float* r = out_res + (size_t)(b * KK + rank) * 4;
    r[0] = (cx - hw)  * 4.0f;
    r[1] = (cy - hh2) * 4.0f;
    r[2] = (cx + hw)  * 4.0f;
    r[3] = (cy + hh2) * 4.0f;
}

// ---------- pass 2: per batch, gather + rank-select + emit -------------------
// (byte-identical to the 62.35us R2 version)
__global__ __launch_bounds__(FTH) void k_final(const float* __restrict__ x,
                                               const float* __restrict__ wh,
                                               const float* __restrict__ reg,
                                               const int* __restrict__ bcnt,
                                               const float* __restrict__ cval,
                                               const int* __restrict__ cidx,
                                               float* __restrict__ out) {
    const int b = blockIdx.x;
    const int t = threadIdx.x;
    __shared__ float sv[SORTCAP];
    __shared__ int   si[SORTCAP];
    __shared__ int   scan[BPB];
    __shared__ int   cnt[BPB];
    __shared__ int   wtot[2];
    __shared__ unsigned long long keys[RANKCAP];   // fast-path packed (val,idx)
    __shared__ int   hist[NBINS];     // fallback only
    __shared__ int   sflags;
    __shared__ int   scnt;
    __shared__ unsigned stk;

    // ---- speculative slot prefetch: overlap gather latency with the scan ----
    // All 3072 slots loaded coalesced into registers before counts are known.
    float spv[SPT]; int spi[SPT];
    {
        const float* vb = cval + (size_t)b * NSLOTS;
        const int*   ib = cidx + (size_t)b * NSLOTS;
#pragma unroll
        for (int i2 = 0; i2 < SPT; ++i2) {
            const int s = t + FTH * i2;
            spv[i2] = vb[s];
            spi[i2] = ib[s];
        }
    }

    if (t == 0) { sflags = 0; scnt = 0; }

    // ---- 2-wave shuffle scan over BPB=128 counts (2 barriers, no HS ping-pong)
    int myscan = 0, myc = 0;
    if (t < BPB) {
        myc = bcnt[b * BPB + t];
        if (myc > SLOT) atomicOr(&sflags, 1);
        cnt[t] = myc;
        int v = myc;
#pragma unroll
        for (int d = 1; d < 64; d <<= 1) {
            int u = __shfl_up(v, d);
            if ((t & 63) >= d) v += u;
        }
        if ((t & 63) == 63) wtot[t >> 6] = v;
        myscan = v;
    }
    __syncthreads();
    if (t < BPB) scan[t] = myscan + ((t >= 64) ? wtot[0] : 0);
    __syncthreads();

    const int total_all = scan[BPB - 1];
    const bool bad = (sflags != 0) || (total_all < KK) || (total_all > SORTCAP);

    const float NEG_INF = __int_as_float(0xFF800000);

    if (!bad && total_all <= RANKCAP) {
        // ---- fast path: packed u64 keys + O(n^2) broadcast rank --------------
        keys[t] = 0ull;                 // pad: smaller than any real key
        __syncthreads();
#pragma unroll
        for (int i2 = 0; i2 < SPT; ++i2) {
            const int s = t + FTH * i2;
            const int blk2 = s / SLOT, pos = s % SLOT;
            const int cc = cnt[blk2];
            if (pos < cc) {
                const int dest = scan[blk2] - cc + pos;   // exclusive prefix + pos
                keys[dest] = ((unsigned long long)fkey(__float_as_uint(spv[i2])) << 32)
                           | (unsigned)(~spi[i2]);        // val desc, idx asc
            }
        }
        __syncthreads();
        const unsigned long long myk = keys[t];
        int rank = 0;
#pragma unroll 8
        for (int j = 0; j < RANKCAP; ++j)
            rank += (keys[j] > myk) ? 1 : 0;              // 1x ds_read_b64 broadcast
        if (rank < KK) {
            const unsigned hi = (unsigned)(myk >> 32);
            const unsigned ub = (hi & 0x80000000u) ? (hi & 0x7FFFFFFFu) : ~hi; // exact inverse of fkey
            emit_one(b, rank, __uint_as_float(ub), (int)~(unsigned)myk, wh, reg, out);
        }
        return;
    }

    int n;
    if (!bad) {
        // ---- guard path setup: place speculative registers into sv/si -------
        n = total_all;
        for (int i = t; i < SORTCAP; i += FTH) { sv[i] = NEG_INF; si[i] = INT_MAX; }
        __syncthreads();
#pragma unroll
        for (int i2 = 0; i2 < SPT; ++i2) {
            const int s = t + FTH * i2;
            const int blk2 = s / SLOT, pos = s % SLOT;
            const int cc = cnt[blk2];
            if (pos < cc) {
                const int dest = scan[blk2] - cc + pos;
                sv[dest] = spv[i2]; si[dest] = spi[i2];
            }
        }
        __syncthreads();
    } else {
        // ---- robust fallback: LDS-histogram top-k over full batch (never-path)
        for (int i = t; i < NBINS; i += FTH) hist[i] = 0;
        for (int i = t; i < SORTCAP; i += FTH) { sv[i] = NEG_INF; si[i] = INT_MAX; }
        __syncthreads();
        const float4* xv = reinterpret_cast<const float4*>(x + (size_t)b * Nn);
        for (int j = t; j < Nn / 4; j += FTH) {
            float4 f = xv[j];
            atomicAdd(&hist[fkey(__float_as_uint(f.x)) >> 20], 1);
            atomicAdd(&hist[fkey(__float_as_uint(f.y)) >> 20], 1);
            atomicAdd(&hist[fkey(__float_as_uint(f.z)) >> 20], 1);
            atomicAdd(&hist[fkey(__float_as_uint(f.w)) >> 20], 1);
        }
        __syncthreads();
        if (t == 0) {
            int cum = 0; unsigned k = 0;
            for (int bin = NBINS - 1; bin >= 0; --bin) {
                cum += hist[bin];
                if (cum >= KK) { k = (unsigned)bin << 20; break; }
            }
            stk = k;
        }
        __syncthreads();
        const unsigned tk = stk;
        for (int j = t; j < Nn / 4; j += FTH) {
            float4 f = xv[j];
            const int i0 = 4 * j;
            float a[4] = {f.x, f.y, f.z, f.w};
#pragma unroll
            for (int cc = 0; cc < 4; ++cc) {
                if (fkey(__float_as_uint(a[cc])) >= tk) {
                    int p = atomicAdd(&scnt, 1);
                    if (p < SORTCAP) { sv[p] = a[cc]; si[p] = i0 + cc; }
                }
            }
        }
        __syncthreads();
        n = scnt; if (n > SORTCAP) n = SORTCAP;
    }

    // ---- guard path: bitonic sort (value desc, tie -> index asc) ------------
    int pad = FTH;
    while (pad < n) pad <<= 1;     // <= SORTCAP
    for (int k = 2; k <= pad; k <<= 1) {
        for (int j = k >> 1; j > 0; j >>= 1) {
            for (int i = t; i < pad; i += FTH) {
                const int ixj = i ^ j;
                if (ixj > i) {
                    float va = sv[i], vb = sv[ixj];
                    int   ia = si[i], ib = si[ixj];
                    const bool a_before_b = (va > vb) || (va == vb && ia < ib);
                    const bool dir = ((i & k) == 0);
                    if (dir ? !a_before_b : a_before_b) {
                        sv[i] = vb; sv[ixj] = va; si[i] = ib; si[ixj] = ia;
                    }
                }
            }
            __syncthreads();
        }
    }
    for (int j = t; j < KK; j += FTH) emit_one(b, j, sv[j], si[j], wh, reg, out);
}

extern "C" void kernel_launch(void* const* d_in, const int* in_sizes, int n_in,
                              void* d_out, int out_size, void* d_ws, size_t ws_size,
                              hipStream_t stream) {
    const float* x   = (const float*)d_in[0];
    const float* wh  = (const float*)d_in[1];
    const float* reg = (const float*)d_in[2];
    float* out = (float*)d_out;

    // workspace layout (no zero-initialization required anywhere)
    char* ws = (char*)d_ws;
    int*   bcnt = (int*)(ws);                                        // [16][128]
    float* cval = (float*)(ws + 16 * 1024);                          // [16][128][24]
    int*   cidx = (int*)(ws + 16 * 1024 + (size_t)Bn * BPB * SLOT * 4);

    dim3 gridS(BPB, Bn);
    k_collect<<<gridS, 256, 0, stream>>>(x, bcnt, cval, cidx);
    k_final  <<<Bn,    FTH, 0, stream>>>(x, wh, reg, bcnt, cval, cidx, out);
}

// Round 6
// 67.790 us; speedup vs baseline: 1.5166x; 1.0306x over previous
//
#include <hip/hip_runtime.h>
#include <stdint.h>
#include <limits.h>

// Problem constants (B, C, H, W fixed by the reference)
#define Bn      16
#define Nn      5242880            // 80*256*256 elements per batch
#define KK      100                // TOPK
#define BPB     128                // blocks per batch for the streaming pass
#define CHUNK   (Nn / BPB)         // 40960 elements per block
#define SLOT    24                 // per-block candidate capacity (mean ~1.3 @ T0=4.0)
#define NSLOTS  (BPB * SLOT)       // 3072 slots per batch
#define SPT     (NSLOTS / 256)     // 12 speculative slots per thread
#define SORTCAP 2048               // guard-path sort capacity
#define RANKCAP 256                // fast-path rank-selection capacity (mean ~166)
#define NBINS   4096               // fallback radix bins
#define T0      4.0f               // fast-path threshold (top-100 cutoff ~4.11 for N(0,1))
#define FTH     256                // k_final block size

typedef float f4v __attribute__((ext_vector_type(4)));

__device__ __forceinline__ unsigned fkey(unsigned u) {
    // monotone float->uint transform: larger float => larger key
    return (u & 0x80000000u) ? ~u : (u | 0x80000000u);
}

// ---------- pass 1: stream x once, per-block private candidate slots ---------
// R6: single-variable A/B vs the 62.35us R2 version — ONLY change is plain
// cacheable loads instead of __builtin_nontemporal_load (still float4/16B,
// still unroll 4). k_final byte-identical to R2.
__global__ __launch_bounds__(256) void k_collect(const float* __restrict__ x,
                                                 int* __restrict__ bcnt,
                                                 float* __restrict__ cval,
                                                 int* __restrict__ cidx) {
    const int b = blockIdx.y, blk = blockIdx.x;
    __shared__ int lcnt;
    if (threadIdx.x == 0) lcnt = 0;
    __syncthreads();
    const f4v* xv = reinterpret_cast<const f4v*>(
        x + (size_t)b * Nn + (size_t)blk * CHUNK);
    const int base = blk * CHUNK;
    float* v  = cval + ((size_t)b * BPB + blk) * SLOT;
    int*   ix = cidx + ((size_t)b * BPB + blk) * SLOT;
#pragma unroll 4
    for (int j = threadIdx.x; j < CHUNK / 4; j += 256) {
        f4v f = xv[j];                                // plain cacheable dwordx4
        const float m = fmaxf(fmaxf(f.x, f.y), fmaxf(f.z, f.w));
        if (m >= T0) {                                 // ~1.3e-4 per-lane: rare
            const int i0 = base + 4 * j;
            if (f.x >= T0) { int p = atomicAdd(&lcnt, 1); if (p < SLOT) { v[p] = f.x; ix[p] = i0;     } }
            if (f.y >= T0) { int p = atomicAdd(&lcnt, 1); if (p < SLOT) { v[p] = f.y; ix[p] = i0 + 1; } }
            if (f.z >= T0) { int p = atomicAdd(&lcnt, 1); if (p < SLOT) { v[p] = f.z; ix[p] = i0 + 2; } }
            if (f.w >= T0) { int p = atomicAdd(&lcnt, 1); if (p < SLOT) { v[p] = f.w; ix[p] = i0 + 3; } }
        }
    }
    __syncthreads();
    if (threadIdx.x == 0) bcnt[b * BPB + blk] = lcnt;   // unconditional: no zeroing needed
}

// ---------- emit one detection at a given rank ----------
__device__ __forceinline__ void emit_one(int b, int rank, float val, int idx,
                                         const float* __restrict__ wh,
                                         const float* __restrict__ reg,
                                         float* __restrict__ out) {
    float* out_cls = out;                 // [16][100]
    float* out_scr = out + Bn * KK;       // [16][100]
    float* out_res = out + 2 * Bn * KK;   // [16][100][4]
    out_cls[b * KK + rank] = (float)idx * (1.0f / 65536.0f);  // exact pow2 division
    out_scr[b * KK + rank] = val;
    const int s  = idx & 65535;
    const float tys = (float)s * (1.0f / 256.0f);             // topk_indices / W (exact)
    const float txs = (float)(s & 255);                       // topk_indices % W
    // reg/wh layout [B,2,H,W]: channel-c at (b, s) = ptr[(b*2+c)*65536 + s]
    const float xo = reg[(size_t)(b * 2 + 0) * 65536 + s];
    const float yo = reg[(size_t)(b * 2 + 1) * 65536 + s];
    const float ww = wh [(size_t)(b * 2 + 0) * 65536 + s];
    const float hh = wh [(size_t)(b * 2 + 1) * 65536 + s];
    const float cx = txs + xo;
    const float cy = tys + yo;
    const float hw  = ww * 0.5f;
    const float hh2 = hh * 0.5f;
    float* r = out_res + (size_t)(b * KK + rank) * 4;
    r[0] = (cx - hw)  * 4.0f;
    r[1] = (cy - hh2) * 4.0f;
    r[2] = (cx + hw)  * 4.0f;
    r[3] = (cy + hh2) * 4.0f;
}

// ---------- pass 2: per batch, gather + rank-select + emit -------------------
// (byte-identical to the 62.35us R2 version)
__global__ __launch_bounds__(FTH) void k_final(const float* __restrict__ x,
                                               const float* __restrict__ wh,
                                               const float* __restrict__ reg,
                                               const int* __restrict__ bcnt,
                                               const float* __restrict__ cval,
                                               const int* __restrict__ cidx,
                                               float* __restrict__ out) {
    const int b = blockIdx.x;
    const int t = threadIdx.x;
    __shared__ float sv[SORTCAP];
    __shared__ int   si[SORTCAP];
    __shared__ int   scan[BPB];
    __shared__ int   cnt[BPB];
    __shared__ int   wtot[2];
    __shared__ unsigned long long keys[RANKCAP];   // fast-path packed (val,idx)
    __shared__ int   hist[NBINS];     // fallback only
    __shared__ int   sflags;
    __shared__ int   scnt;
    __shared__ unsigned stk;

    // ---- speculative slot prefetch: overlap gather latency with the scan ----
    // All 3072 slots loaded coalesced into registers before counts are known.
    float spv[SPT]; int spi[SPT];
    {
        const float* vb = cval + (size_t)b * NSLOTS;
        const int*   ib = cidx + (size_t)b * NSLOTS;
#pragma unroll
        for (int i2 = 0; i2 < SPT; ++i2) {
            const int s = t + FTH * i2;
            spv[i2] = vb[s];
            spi[i2] = ib[s];
        }
    }

    if (t == 0) { sflags = 0; scnt = 0; }

    // ---- 2-wave shuffle scan over BPB=128 counts (2 barriers, no HS ping-pong)
    int myscan = 0, myc = 0;
    if (t < BPB) {
        myc = bcnt[b * BPB + t];
        if (myc > SLOT) atomicOr(&sflags, 1);
        cnt[t] = myc;
        int v = myc;
#pragma unroll
        for (int d = 1; d < 64; d <<= 1) {
            int u = __shfl_up(v, d);
            if ((t & 63) >= d) v += u;
        }
        if ((t & 63) == 63) wtot[t >> 6] = v;
        myscan = v;
    }
    __syncthreads();
    if (t < BPB) scan[t] = myscan + ((t >= 64) ? wtot[0] : 0);
    __syncthreads();

    const int total_all = scan[BPB - 1];
    const bool bad = (sflags != 0) || (total_all < KK) || (total_all > SORTCAP);

    const float NEG_INF = __int_as_float(0xFF800000);

    if (!bad && total_all <= RANKCAP) {
        // ---- fast path: packed u64 keys + O(n^2) broadcast rank --------------
        keys[t] = 0ull;                 // pad: smaller than any real key
        __syncthreads();
#pragma unroll
        for (int i2 = 0; i2 < SPT; ++i2) {
            const int s = t + FTH * i2;
            const int blk2 = s / SLOT, pos = s % SLOT;
            const int cc = cnt[blk2];
            if (pos < cc) {
                const int dest = scan[blk2] - cc + pos;   // exclusive prefix + pos
                keys[dest] = ((unsigned long long)fkey(__float_as_uint(spv[i2])) << 32)
                           | (unsigned)(~spi[i2]);        // val desc, idx asc
            }
        }
        __syncthreads();
        const unsigned long long myk = keys[t];
        int rank = 0;
#pragma unroll 8
        for (int j = 0; j < RANKCAP; ++j)
            rank += (keys[j] > myk) ? 1 : 0;              // 1x ds_read_b64 broadcast
        if (rank < KK) {
            const unsigned hi = (unsigned)(myk >> 32);
            const unsigned ub = (hi & 0x80000000u) ? (hi & 0x7FFFFFFFu) : ~hi; // exact inverse of fkey
            emit_one(b, rank, __uint_as_float(ub), (int)~(unsigned)myk, wh, reg, out);
        }
        return;
    }

    int n;
    if (!bad) {
        // ---- guard path setup: place speculative registers into sv/si -------
        n = total_all;
        for (int i = t; i < SORTCAP; i += FTH) { sv[i] = NEG_INF; si[i] = INT_MAX; }
        __syncthreads();
#pragma unroll
        for (int i2 = 0; i2 < SPT; ++i2) {
            const int s = t + FTH * i2;
            const int blk2 = s / SLOT, pos = s % SLOT;
            const int cc = cnt[blk2];
            if (pos < cc) {
                const int dest = scan[blk2] - cc + pos;
                sv[dest] = spv[i2]; si[dest] = spi[i2];
            }
        }
        __syncthreads();
    } else {
        // ---- robust fallback: LDS-histogram top-k over full batch (never-path)
        for (int i = t; i < NBINS; i += FTH) hist[i] = 0;
        for (int i = t; i < SORTCAP; i += FTH) { sv[i] = NEG_INF; si[i] = INT_MAX; }
        __syncthreads();
        const float4* xv = reinterpret_cast<const float4*>(x + (size_t)b * Nn);
        for (int j = t; j < Nn / 4; j += FTH) {
            float4 f = xv[j];
            atomicAdd(&hist[fkey(__float_as_uint(f.x)) >> 20], 1);
            atomicAdd(&hist[fkey(__float_as_uint(f.y)) >> 20], 1);
            atomicAdd(&hist[fkey(__float_as_uint(f.z)) >> 20], 1);
            atomicAdd(&hist[fkey(__float_as_uint(f.w)) >> 20], 1);
        }
        __syncthreads();
        if (t == 0) {
            int cum = 0; unsigned k = 0;
            for (int bin = NBINS - 1; bin >= 0; --bin) {
                cum += hist[bin];
                if (cum >= KK) { k = (unsigned)bin << 20; break; }
            }
            stk = k;
        }
        __syncthreads();
        const unsigned tk = stk;
        for (int j = t; j < Nn / 4; j += FTH) {
            float4 f = xv[j];
            const int i0 = 4 * j;
            float a[4] = {f.x, f.y, f.z, f.w};
#pragma unroll
            for (int cc = 0; cc < 4; ++cc) {
                if (fkey(__float_as_uint(a[cc])) >= tk) {
                    int p = atomicAdd(&scnt, 1);
                    if (p < SORTCAP) { sv[p] = a[cc]; si[p] = i0 + cc; }
                }
            }
        }
        __syncthreads();
        n = scnt; if (n > SORTCAP) n = SORTCAP;
    }

    // ---- guard path: bitonic sort (value desc, tie -> index asc) ------------
    int pad = FTH;
    while (pad < n) pad <<= 1;     // <= SORTCAP
    for (int k = 2; k <= pad; k <<= 1) {
        for (int j = k >> 1; j > 0; j >>= 1) {
            for (int i = t; i < pad; i += FTH) {
                const int ixj = i ^ j;
                if (ixj > i) {
                    float va = sv[i], vb = sv[ixj];
                    int   ia = si[i], ib = si[ixj];
                    const bool a_before_b = (va > vb) || (va == vb && ia < ib);
                    const bool dir = ((i & k) == 0);
                    if (dir ? !a_before_b : a_before_b) {
                        sv[i] = vb; sv[ixj] = va; si[i] = ib; si[ixj] = ia;
                    }
                }
            }
            __syncthreads();
        }
    }
    for (int j = t; j < KK; j += FTH) emit_one(b, j, sv[j], si[j], wh, reg, out);
}

extern "C" void kernel_launch(void* const* d_in, const int* in_sizes, int n_in,
                              void* d_out, int out_size, void* d_ws, size_t ws_size,
                              hipStream_t stream) {
    const float* x   = (const float*)d_in[0];
    const float* wh  = (const float*)d_in[1];
    const float* reg = (const float*)d_in[2];
    float* out = (float*)d_out;

    // workspace layout (no zero-initialization required anywhere)
    char* ws = (char*)d_ws;
    int*   bcnt = (int*)(ws);                                        // [16][128]
    float* cval = (float*)(ws + 16 * 1024);                          // [16][128][24]
    int*   cidx = (int*)(ws + 16 * 1024 + (size_t)Bn * BPB * SLOT * 4);

    dim3 gridS(BPB, Bn);
    k_collect<<<gridS, 256, 0, stream>>>(x, bcnt, cval, cidx);
    k_final  <<<Bn,    FTH, 0, stream>>>(x, wh, reg, bcnt, cval, cidx, out);
}

// Round 7
// 60.586 us; speedup vs baseline: 1.6970x; 1.1189x over previous
//
#include <hip/hip_runtime.h>
#include <stdint.h>
#include <limits.h>

// Problem constants (B, C, H, W fixed by the reference)
#define Bn      16
#define Nn      5242880            // 80*256*256 elements per batch
#define KK      100                // TOPK
#define BPB     128                // blocks per batch for the streaming pass
#define CHUNK   (Nn / BPB)         // 40960 elements per block
#define SLOT    24                 // per-block candidate capacity (mean ~1.3 @ T0=4.0)
#define NSLOTS  (BPB * SLOT)       // 3072 slots per batch
#define SPT     (NSLOTS / 256)     // 12 speculative slots per thread
#define SORTCAP 2048               // guard-path sort capacity
#define RANKCAP 256                // fast-path rank-selection capacity (mean ~166)
#define NBINS   4096               // fallback radix bins
#define T0      4.0f               // fast-path threshold (top-100 cutoff ~4.11 for N(0,1))
#define FTH     256                // k_final block size
#define MLP     8                  // explicit load batch depth (R7 variable)

typedef float f4v __attribute__((ext_vector_type(4)));

__device__ __forceinline__ unsigned fkey(unsigned u) {
    // monotone float->uint transform: larger float => larger key
    return (u & 0x80000000u) ? ~u : (u | 0x80000000u);
}

// ---------- pass 1: stream x once, per-block private candidate slots ---------
// R7: single-variable vs the 62.35us R2 version — NT loads and 16B/lane kept;
// ONLY change is an explicit 8-deep load batch (issue 8 NT dwordx4 back-to-
// back, then process all 8) to double per-wave outstanding VMEM.
// __launch_bounds__(256,8) pins VGPR<=64 so the exactly-resident 8-block/CU
// occupancy is preserved.
__global__ __launch_bounds__(256, 8) void k_collect(const float* __restrict__ x,
                                                    int* __restrict__ bcnt,
                                                    float* __restrict__ cval,
                                                    int* __restrict__ cidx) {
    const int b = blockIdx.y, blk = blockIdx.x;
    __shared__ int lcnt;
    if (threadIdx.x == 0) lcnt = 0;
    __syncthreads();
    const f4v* xv = reinterpret_cast<const f4v*>(
        x + (size_t)b * Nn + (size_t)blk * CHUNK);
    const int base = blk * CHUNK;
    float* v  = cval + ((size_t)b * BPB + blk) * SLOT;
    int*   ix = cidx + ((size_t)b * BPB + blk) * SLOT;
    // CHUNK/4 = 10240 f4v elements; 256 threads -> 40 strided iterations
    // = 5 groups of MLP=8.
#pragma unroll 1
    for (int g = 0; g < (CHUNK / 4 / 256) / MLP; ++g) {
        f4v f[MLP];
#pragma unroll
        for (int u = 0; u < MLP; ++u)
            f[u] = __builtin_nontemporal_load(
                &xv[threadIdx.x + (size_t)(g * MLP + u) * 256]);
#pragma unroll
        for (int u = 0; u < MLP; ++u) {
            const float m = fmaxf(fmaxf(f[u].x, f[u].y), fmaxf(f[u].z, f[u].w));
            if (m >= T0) {                             // ~1.3e-4 per-lane: rare
                const int i0 = base + 4 * (threadIdx.x + (g * MLP + u) * 256);
                if (f[u].x >= T0) { int p = atomicAdd(&lcnt, 1); if (p < SLOT) { v[p] = f[u].x; ix[p] = i0;     } }
                if (f[u].y >= T0) { int p = atomicAdd(&lcnt, 1); if (p < SLOT) { v[p] = f[u].y; ix[p] = i0 + 1; } }
                if (f[u].z >= T0) { int p = atomicAdd(&lcnt, 1); if (p < SLOT) { v[p] = f[u].z; ix[p] = i0 + 2; } }
                if (f[u].w >= T0) { int p = atomicAdd(&lcnt, 1); if (p < SLOT) { v[p] = f[u].w; ix[p] = i0 + 3; } }
            }
        }
    }
    __syncthreads();
    if (threadIdx.x == 0) bcnt[b * BPB + blk] = lcnt;   // unconditional: no zeroing needed
}

// ---------- emit one detection at a given rank ----------
__device__ __forceinline__ void emit_one(int b, int rank, float val, int idx,
                                         const float* __restrict__ wh,
                                         const float* __restrict__ reg,
                                         float* __restrict__ out) {
    float* out_cls = out;                 // [16][100]
    float* out_scr = out + Bn * KK;       // [16][100]
    float* out_res = out + 2 * Bn * KK;   // [16][100][4]
    out_cls[b * KK + rank] = (float)idx * (1.0f / 65536.0f);  // exact pow2 division
    out_scr[b * KK + rank] = val;
    const int s  = idx & 65535;
    const float tys = (float)s * (1.0f / 256.0f);             // topk_indices / W (exact)
    const float txs = (float)(s & 255);                       // topk_indices % W
    // reg/wh layout [B,2,H,W]: channel-c at (b, s) = ptr[(b*2+c)*65536 + s]
    const float xo = reg[(size_t)(b * 2 + 0) * 65536 + s];
    const float yo = reg[(size_t)(b * 2 + 1) * 65536 + s];
    const float ww = wh [(size_t)(b * 2 + 0) * 65536 + s];
    const float hh = wh [(size_t)(b * 2 + 1) * 65536 + s];
    const float cx = txs + xo;
    const float cy = tys + yo;
    const float hw  = ww * 0.5f;
    const float hh2 = hh * 0.5f;
    float* r = out_res + (size_t)(b * KK + rank) * 4;
    r[0] = (cx - hw)  * 4.0f;
    r[1] = (cy - hh2) * 4.0f;
    r[2] = (cx + hw)  * 4.0f;
    r[3] = (cy + hh2) * 4.0f;
}

// ---------- pass 2: per batch, gather + rank-select + emit -------------------
// (byte-identical to the 62.35us R2 version)
__global__ __launch_bounds__(FTH) void k_final(const float* __restrict__ x,
                                               const float* __restrict__ wh,
                                               const float* __restrict__ reg,
                                               const int* __restrict__ bcnt,
                                               const float* __restrict__ cval,
                                               const int* __restrict__ cidx,
                                               float* __restrict__ out) {
    const int b = blockIdx.x;
    const int t = threadIdx.x;
    __shared__ float sv[SORTCAP];
    __shared__ int   si[SORTCAP];
    __shared__ int   scan[BPB];
    __shared__ int   cnt[BPB];
    __shared__ int   wtot[2];
    __shared__ unsigned long long keys[RANKCAP];   // fast-path packed (val,idx)
    __shared__ int   hist[NBINS];     // fallback only
    __shared__ int   sflags;
    __shared__ int   scnt;
    __shared__ unsigned stk;

    // ---- speculative slot prefetch: overlap gather latency with the scan ----
    // All 3072 slots loaded coalesced into registers before counts are known.
    float spv[SPT]; int spi[SPT];
    {
        const float* vb = cval + (size_t)b * NSLOTS;
        const int*   ib = cidx + (size_t)b * NSLOTS;
#pragma unroll
        for (int i2 = 0; i2 < SPT; ++i2) {
            const int s = t + FTH * i2;
            spv[i2] = vb[s];
            spi[i2] = ib[s];
        }
    }

    if (t == 0) { sflags = 0; scnt = 0; }

    // ---- 2-wave shuffle scan over BPB=128 counts (2 barriers, no HS ping-pong)
    int myscan = 0, myc = 0;
    if (t < BPB) {
        myc = bcnt[b * BPB + t];
        if (myc > SLOT) atomicOr(&sflags, 1);
        cnt[t] = myc;
        int v = myc;
#pragma unroll
        for (int d = 1; d < 64; d <<= 1) {
            int u = __shfl_up(v, d);
            if ((t & 63) >= d) v += u;
        }
        if ((t & 63) == 63) wtot[t >> 6] = v;
        myscan = v;
    }
    __syncthreads();
    if (t < BPB) scan[t] = myscan + ((t >= 64) ? wtot[0] : 0);
    __syncthreads();

    const int total_all = scan[BPB - 1];
    const bool bad = (sflags != 0) || (total_all < KK) || (total_all > SORTCAP);

    const float NEG_INF = __int_as_float(0xFF800000);

    if (!bad && total_all <= RANKCAP) {
        // ---- fast path: packed u64 keys + O(n^2) broadcast rank --------------
        keys[t] = 0ull;                 // pad: smaller than any real key
        __syncthreads();
#pragma unroll
        for (int i2 = 0; i2 < SPT; ++i2) {
            const int s = t + FTH * i2;
            const int blk2 = s / SLOT, pos = s % SLOT;
            const int cc = cnt[blk2];
            if (pos < cc) {
                const int dest = scan[blk2] - cc + pos;   // exclusive prefix + pos
                keys[dest] = ((unsigned long long)fkey(__float_as_uint(spv[i2])) << 32)
                           | (unsigned)(~spi[i2]);        // val desc, idx asc
            }
        }
        __syncthreads();
        const unsigned long long myk = keys[t];
        int rank = 0;
#pragma unroll 8
        for (int j = 0; j < RANKCAP; ++j)
            rank += (keys[j] > myk) ? 1 : 0;              // 1x ds_read_b64 broadcast
        if (rank < KK) {
            const unsigned hi = (unsigned)(myk >> 32);
            const unsigned ub = (hi & 0x80000000u) ? (hi & 0x7FFFFFFFu) : ~hi; // exact inverse of fkey
            emit_one(b, rank, __uint_as_float(ub), (int)~(unsigned)myk, wh, reg, out);
        }
        return;
    }

    int n;
    if (!bad) {
        // ---- guard path setup: place speculative registers into sv/si -------
        n = total_all;
        for (int i = t; i < SORTCAP; i += FTH) { sv[i] = NEG_INF; si[i] = INT_MAX; }
        __syncthreads();
#pragma unroll
        for (int i2 = 0; i2 < SPT; ++i2) {
            const int s = t + FTH * i2;
            const int blk2 = s / SLOT, pos = s % SLOT;
            const int cc = cnt[blk2];
            if (pos < cc) {
                const int dest = scan[blk2] - cc + pos;
                sv[dest] = spv[i2]; si[dest] = spi[i2];
            }
        }
        __syncthreads();
    } else {
        // ---- robust fallback: LDS-histogram top-k over full batch (never-path)
        for (int i = t; i < NBINS; i += FTH) hist[i] = 0;
        for (int i = t; i < SORTCAP; i += FTH) { sv[i] = NEG_INF; si[i] = INT_MAX; }
        __syncthreads();
        const float4* xv = reinterpret_cast<const float4*>(x + (size_t)b * Nn);
        for (int j = t; j < Nn / 4; j += FTH) {
            float4 f = xv[j];
            atomicAdd(&hist[fkey(__float_as_uint(f.x)) >> 20], 1);
            atomicAdd(&hist[fkey(__float_as_uint(f.y)) >> 20], 1);
            atomicAdd(&hist[fkey(__float_as_uint(f.z)) >> 20], 1);
            atomicAdd(&hist[fkey(__float_as_uint(f.w)) >> 20], 1);
        }
        __syncthreads();
        if (t == 0) {
            int cum = 0; unsigned k = 0;
            for (int bin = NBINS - 1; bin >= 0; --bin) {
                cum += hist[bin];
                if (cum >= KK) { k = (unsigned)bin << 20; break; }
            }
            stk = k;
        }
        __syncthreads();
        const unsigned tk = stk;
        for (int j = t; j < Nn / 4; j += FTH) {
            float4 f = xv[j];
            const int i0 = 4 * j;
            float a[4] = {f.x, f.y, f.z, f.w};
#pragma unroll
            for (int cc = 0; cc < 4; ++cc) {
                if (fkey(__float_as_uint(a[cc])) >= tk) {
                    int p = atomicAdd(&scnt, 1);
                    if (p < SORTCAP) { sv[p] = a[cc]; si[p] = i0 + cc; }
                }
            }
        }
        __syncthreads();
        n = scnt; if (n > SORTCAP) n = SORTCAP;
    }

    // ---- guard path: bitonic sort (value desc, tie -> index asc) ------------
    int pad = FTH;
    while (pad < n) pad <<= 1;     // <= SORTCAP
    for (int k = 2; k <= pad; k <<= 1) {
        for (int j = k >> 1; j > 0; j >>= 1) {
            for (int i = t; i < pad; i += FTH) {
                const int ixj = i ^ j;
                if (ixj > i) {
                    float va = sv[i], vb = sv[ixj];
                    int   ia = si[i], ib = si[ixj];
                    const bool a_before_b = (va > vb) || (va == vb && ia < ib);
                    const bool dir = ((i & k) == 0);
                    if (dir ? !a_before_b : a_before_b) {
                        sv[i] = vb; sv[ixj] = va; si[i] = ib; si[ixj] = ia;
                    }
                }
            }
            __syncthreads();
        }
    }
    for (int j = t; j < KK; j += FTH) emit_one(b, j, sv[j], si[j], wh, reg, out);
}

extern "C" void kernel_launch(void* const* d_in, const int* in_sizes, int n_in,
                              void* d_out, int out_size, void* d_ws, size_t ws_size,
                              hipStream_t stream) {
    const float* x   = (const float*)d_in[0];
    const float* wh  = (const float*)d_in[1];
    const float* reg = (const float*)d_in[2];
    float* out = (float*)d_out;

    // workspace layout (no zero-initialization required anywhere)
    char* ws = (char*)d_ws;
    int*   bcnt = (int*)(ws);                                        // [16][128]
    float* cval = (float*)(ws + 16 * 1024);                          // [16][128][24]
    int*   cidx = (int*)(ws + 16 * 1024 + (size_t)Bn * BPB * SLOT * 4);

    dim3 gridS(BPB, Bn);
    k_collect<<<gridS, 256, 0, stream>>>(x, bcnt, cval, cidx);
    k_final  <<<Bn,    FTH, 0, stream>>>(x, wh, reg, bcnt, cval, cidx, out);
}

// Round 8
// 60.203 us; speedup vs baseline: 1.7078x; 1.0064x over previous
//
#include <hip/hip_runtime.h>
#include <stdint.h>
#include <limits.h>

// Problem constants (B, C, H, W fixed by the reference)
#define Bn      16
#define Nn      5242880            // 80*256*256 elements per batch
#define KK      100                // TOPK
#define BPB     128                // blocks per batch for the streaming pass
#define CHUNK   (Nn / BPB)         // 40960 elements per block
#define SLOT    24                 // per-block candidate capacity (mean ~1.3 @ T0=4.0)
#define NSLOTS  (BPB * SLOT)       // 3072 slots per batch
#define SPT     (NSLOTS / 256)     // 12 speculative slots per thread
#define SORTCAP 2048               // guard-path sort capacity
#define RANKCAP 256                // fast-path rank-selection capacity (mean ~166)
#define NBINS   4096               // fallback radix bins
#define T0      4.0f               // fast-path threshold (top-100 cutoff ~4.11 for N(0,1))
#define FTH     256                // k_final block size
#define MLP     10                 // explicit load batch depth (R8 variable: 8 -> 10)

typedef float f4v __attribute__((ext_vector_type(4)));

__device__ __forceinline__ unsigned fkey(unsigned u) {
    // monotone float->uint transform: larger float => larger key
    return (u & 0x80000000u) ? ~u : (u | 0x80000000u);
}

// ---------- pass 1: stream x once, per-block private candidate slots ---------
// R8: single-variable vs the 60.59us R7 version — ONLY change is load batch
// depth MLP 8 -> 10 (40 iters = 4 groups of 10). NT + 16B/lane retained.
// 40 data VGPRs + addressing must stay under the 64-VGPR cap from
// __launch_bounds__(256,8); a spill would show as a regression (revert).
__global__ __launch_bounds__(256, 8) void k_collect(const float* __restrict__ x,
                                                    int* __restrict__ bcnt,
                                                    float* __restrict__ cval,
                                                    int* __restrict__ cidx) {
    const int b = blockIdx.y, blk = blockIdx.x;
    __shared__ int lcnt;
    if (threadIdx.x == 0) lcnt = 0;
    __syncthreads();
    const f4v* xv = reinterpret_cast<const f4v*>(
        x + (size_t)b * Nn + (size_t)blk * CHUNK);
    const int base = blk * CHUNK;
    float* v  = cval + ((size_t)b * BPB + blk) * SLOT;
    int*   ix = cidx + ((size_t)b * BPB + blk) * SLOT;
    // CHUNK/4 = 10240 f4v elements; 256 threads -> 40 strided iterations
    // = 4 groups of MLP=10.
#pragma unroll 1
    for (int g = 0; g < (CHUNK / 4 / 256) / MLP; ++g) {
        f4v f[MLP];
#pragma unroll
        for (int u = 0; u < MLP; ++u)
            f[u] = __builtin_nontemporal_load(
                &xv[threadIdx.x + (size_t)(g * MLP + u) * 256]);
#pragma unroll
        for (int u = 0; u < MLP; ++u) {
            const float m = fmaxf(fmaxf(f[u].x, f[u].y), fmaxf(f[u].z, f[u].w));
            if (m >= T0) {                             // ~1.3e-4 per-lane: rare
                const int i0 = base + 4 * (threadIdx.x + (g * MLP + u) * 256);
                if (f[u].x >= T0) { int p = atomicAdd(&lcnt, 1); if (p < SLOT) { v[p] = f[u].x; ix[p] = i0;     } }
                if (f[u].y >= T0) { int p = atomicAdd(&lcnt, 1); if (p < SLOT) { v[p] = f[u].y; ix[p] = i0 + 1; } }
                if (f[u].z >= T0) { int p = atomicAdd(&lcnt, 1); if (p < SLOT) { v[p] = f[u].z; ix[p] = i0 + 2; } }
                if (f[u].w >= T0) { int p = atomicAdd(&lcnt, 1); if (p < SLOT) { v[p] = f[u].w; ix[p] = i0 + 3; } }
            }
        }
    }
    __syncthreads();
    if (threadIdx.x == 0) bcnt[b * BPB + blk] = lcnt;   // unconditional: no zeroing needed
}

// ---------- emit one detection at a given rank ----------
__device__ __forceinline__ void emit_one(int b, int rank, float val, int idx,
                                         const float* __restrict__ wh,
                                         const float* __restrict__ reg,
                                         float* __restrict__ out) {
    float* out_cls = out;                 // [16][100]
    float* out_scr = out + Bn * KK;       // [16][100]
    float* out_res = out + 2 * Bn * KK;   // [16][100][4]
    out_cls[b * KK + rank] = (float)idx * (1.0f / 65536.0f);  // exact pow2 division
    out_scr[b * KK + rank] = val;
    const int s  = idx & 65535;
    const float tys = (float)s * (1.0f / 256.0f);             // topk_indices / W (exact)
    const float txs = (float)(s & 255);                       // topk_indices % W
    // reg/wh layout [B,2,H,W]: channel-c at (b, s) = ptr[(b*2+c)*65536 + s]
    const float xo = reg[(size_t)(b * 2 + 0) * 65536 + s];
    const float yo = reg[(size_t)(b * 2 + 1) * 65536 + s];
    const float ww = wh [(size_t)(b * 2 + 0) * 65536 + s];
    const float hh = wh [(size_t)(b * 2 + 1) * 65536 + s];
    const float cx = txs + xo;
    const float cy = tys + yo;
    const float hw  = ww * 0.5f;
    const float hh2 = hh * 0.5f;
    float* r = out_res + (size_t)(b * KK + rank) * 4;
    r[0] = (cx - hw)  * 4.0f;
    r[1] = (cy - hh2) * 4.0f;
    r[2] = (cx + hw)  * 4.0f;
    r[3] = (cy + hh2) * 4.0f;
}

// ---------- pass 2: per batch, gather + rank-select + emit -------------------
// (byte-identical to the 62.35us R2 version)
__global__ __launch_bounds__(FTH) void k_final(const float* __restrict__ x,
                                               const float* __restrict__ wh,
                                               const float* __restrict__ reg,
                                               const int* __restrict__ bcnt,
                                               const float* __restrict__ cval,
                                               const int* __restrict__ cidx,
                                               float* __restrict__ out) {
    const int b = blockIdx.x;
    const int t = threadIdx.x;
    __shared__ float sv[SORTCAP];
    __shared__ int   si[SORTCAP];
    __shared__ int   scan[BPB];
    __shared__ int   cnt[BPB];
    __shared__ int   wtot[2];
    __shared__ unsigned long long keys[RANKCAP];   // fast-path packed (val,idx)
    __shared__ int   hist[NBINS];     // fallback only
    __shared__ int   sflags;
    __shared__ int   scnt;
    __shared__ unsigned stk;

    // ---- speculative slot prefetch: overlap gather latency with the scan ----
    // All 3072 slots loaded coalesced into registers before counts are known.
    float spv[SPT]; int spi[SPT];
    {
        const float* vb = cval + (size_t)b * NSLOTS;
        const int*   ib = cidx + (size_t)b * NSLOTS;
#pragma unroll
        for (int i2 = 0; i2 < SPT; ++i2) {
            const int s = t + FTH * i2;
            spv[i2] = vb[s];
            spi[i2] = ib[s];
        }
    }

    if (t == 0) { sflags = 0; scnt = 0; }

    // ---- 2-wave shuffle scan over BPB=128 counts (2 barriers, no HS ping-pong)
    int myscan = 0, myc = 0;
    if (t < BPB) {
        myc = bcnt[b * BPB + t];
        if (myc > SLOT) atomicOr(&sflags, 1);
        cnt[t] = myc;
        int v = myc;
#pragma unroll
        for (int d = 1; d < 64; d <<= 1) {
            int u = __shfl_up(v, d);
            if ((t & 63) >= d) v += u;
        }
        if ((t & 63) == 63) wtot[t >> 6] = v;
        myscan = v;
    }
    __syncthreads();
    if (t < BPB) scan[t] = myscan + ((t >= 64) ? wtot[0] : 0);
    __syncthreads();

    const int total_all = scan[BPB - 1];
    const bool bad = (sflags != 0) || (total_all < KK) || (total_all > SORTCAP);

    const float NEG_INF = __int_as_float(0xFF800000);

    if (!bad && total_all <= RANKCAP) {
        // ---- fast path: packed u64 keys + O(n^2) broadcast rank --------------
        keys[t] = 0ull;                 // pad: smaller than any real key
        __syncthreads();
#pragma unroll
        for (int i2 = 0; i2 < SPT; ++i2) {
            const int s = t + FTH * i2;
            const int blk2 = s / SLOT, pos = s % SLOT;
            const int cc = cnt[blk2];
            if (pos < cc) {
                const int dest = scan[blk2] - cc + pos;   // exclusive prefix + pos
                keys[dest] = ((unsigned long long)fkey(__float_as_uint(spv[i2])) << 32)
                           | (unsigned)(~spi[i2]);        // val desc, idx asc
            }
        }
        __syncthreads();
        const unsigned long long myk = keys[t];
        int rank = 0;
#pragma unroll 8
        for (int j = 0; j < RANKCAP; ++j)
            rank += (keys[j] > myk) ? 1 : 0;              // 1x ds_read_b64 broadcast
        if (rank < KK) {
            const unsigned hi = (unsigned)(myk >> 32);
            const unsigned ub = (hi & 0x80000000u) ? (hi & 0x7FFFFFFFu) : ~hi; // exact inverse of fkey
            emit_one(b, rank, __uint_as_float(ub), (int)~(unsigned)myk, wh, reg, out);
        }
        return;
    }

    int n;
    if (!bad) {
        // ---- guard path setup: place speculative registers into sv/si -------
        n = total_all;
        for (int i = t; i < SORTCAP; i += FTH) { sv[i] = NEG_INF; si[i] = INT_MAX; }
        __syncthreads();
#pragma unroll
        for (int i2 = 0; i2 < SPT; ++i2) {
            const int s = t + FTH * i2;
            const int blk2 = s / SLOT, pos = s % SLOT;
            const int cc = cnt[blk2];
            if (pos < cc) {
                const int dest = scan[blk2] - cc + pos;
                sv[dest] = spv[i2]; si[dest] = spi[i2];
            }
        }
        __syncthreads();
    } else {
        // ---- robust fallback: LDS-histogram top-k over full batch (never-path)
        for (int i = t; i < NBINS; i += FTH) hist[i] = 0;
        for (int i = t; i < SORTCAP; i += FTH) { sv[i] = NEG_INF; si[i] = INT_MAX; }
        __syncthreads();
        const float4* xv = reinterpret_cast<const float4*>(x + (size_t)b * Nn);
        for (int j = t; j < Nn / 4; j += FTH) {
            float4 f = xv[j];
            atomicAdd(&hist[fkey(__float_as_uint(f.x)) >> 20], 1);
            atomicAdd(&hist[fkey(__float_as_uint(f.y)) >> 20], 1);
            atomicAdd(&hist[fkey(__float_as_uint(f.z)) >> 20], 1);
            atomicAdd(&hist[fkey(__float_as_uint(f.w)) >> 20], 1);
        }
        __syncthreads();
        if (t == 0) {
            int cum = 0; unsigned k = 0;
            for (int bin = NBINS - 1; bin >= 0; --bin) {
                cum += hist[bin];
                if (cum >= KK) { k = (unsigned)bin << 20; break; }
            }
            stk = k;
        }
        __syncthreads();
        const unsigned tk = stk;
        for (int j = t; j < Nn / 4; j += FTH) {
            float4 f = xv[j];
            const int i0 = 4 * j;
            float a[4] = {f.x, f.y, f.z, f.w};
#pragma unroll
            for (int cc = 0; cc < 4; ++cc) {
                if (fkey(__float_as_uint(a[cc])) >= tk) {
                    int p = atomicAdd(&scnt, 1);
                    if (p < SORTCAP) { sv[p] = a[cc]; si[p] = i0 + cc; }
                }
            }
        }
        __syncthreads();
        n = scnt; if (n > SORTCAP) n = SORTCAP;
    }

    // ---- guard path: bitonic sort (value desc, tie -> index asc) ------------
    int pad = FTH;
    while (pad < n) pad <<= 1;     // <= SORTCAP
    for (int k = 2; k <= pad; k <<= 1) {
        for (int j = k >> 1; j > 0; j >>= 1) {
            for (int i = t; i < pad; i += FTH) {
                const int ixj = i ^ j;
                if (ixj > i) {
                    float va = sv[i], vb = sv[ixj];
                    int   ia = si[i], ib = si[ixj];
                    const bool a_before_b = (va > vb) || (va == vb && ia < ib);
                    const bool dir = ((i & k) == 0);
                    if (dir ? !a_before_b : a_before_b) {
                        sv[i] = vb; sv[ixj] = va; si[i] = ib; si[ixj] = ia;
                    }
                }
            }
            __syncthreads();
        }
    }
    for (int j = t; j < KK; j += FTH) emit_one(b, j, sv[j], si[j], wh, reg, out);
}

extern "C" void kernel_launch(void* const* d_in, const int* in_sizes, int n_in,
                              void* d_out, int out_size, void* d_ws, size_t ws_size,
                              hipStream_t stream) {
    const float* x   = (const float*)d_in[0];
    const float* wh  = (const float*)d_in[1];
    const float* reg = (const float*)d_in[2];
    float* out = (float*)d_out;

    // workspace layout (no zero-initialization required anywhere)
    char* ws = (char*)d_ws;
    int*   bcnt = (int*)(ws);                                        // [16][128]
    float* cval = (float*)(ws + 16 * 1024);                          // [16][128][24]
    int*   cidx = (int*)(ws + 16 * 1024 + (size_t)Bn * BPB * SLOT * 4);

    dim3 gridS(BPB, Bn);
    k_collect<<<gridS, 256, 0, stream>>>(x, bcnt, cval, cidx);
    k_final  <<<Bn,    FTH, 0, stream>>>(x, wh, reg, bcnt, cval, cidx, out);
}